// Round 8
// baseline (301.974 us; speedup 1.0000x reference)
//
#include <hip/hip_runtime.h>
#include <math.h>

#define Bsz 2
#define Ssz 2048
#define Esz 1024
#define Hn  16
#define Dd  64
#define PADC 72    // attn LDS pitch in shorts (144 B)
#define TP   136   // proj epilogue LDS tile pitch in shorts (272 B)
#define FP   68    // final epilogue LDS tile pitch in floats (272 B)

typedef unsigned short ushort_t;
typedef short bf16x8 __attribute__((ext_vector_type(8)));
typedef short bf16x4 __attribute__((ext_vector_type(4)));
typedef float f32x4 __attribute__((ext_vector_type(4)));

#define GLD16(g, l) __builtin_amdgcn_global_load_lds(                        \
    (const __attribute__((address_space(1))) unsigned int*)(g),              \
    (__attribute__((address_space(3))) unsigned int*)(l), 16, 0, 0)

#define KF 0.045084220027780106f   // (1/sqrt(E)) * log2(e), folded into Q

#define MFMA32(a, b, c) __builtin_amdgcn_mfma_f32_16x16x32_bf16((a), (b), (c), 0, 0, 0)
#define MFMA16(a, b, c) __builtin_amdgcn_mfma_f32_16x16x16bf16_1k((a), (b), (c), 0, 0, 0)

// ---------------------------------------------------------------------------
__device__ inline ushort_t bf16_rn(float x)
{
    unsigned u = __float_as_uint(x);
    return (ushort_t)((u + 0x7FFFu + ((u >> 16) & 1u)) >> 16);
}

// ---------------------------------------------------------------------------
// fp32 -> bf16 convert (7 tensors) + RoPE table build (z=7).
// ---------------------------------------------------------------------------
__global__ __launch_bounds__(256) void cvt_kernel(
    const float* s0, const float* s1, const float* s2, const float* s3,
    const float* s4, const float* s5, const float* s6,
    ushort_t* d0, ushort_t* d1, ushort_t* d2, ushort_t* d3,
    ushort_t* d4, ushort_t* d5, ushort_t* d6,
    float* tc, float* ts, int n_big, int n_small)
{
    if (blockIdx.z == 7) {
        const int idx = blockIdx.x * 256 + threadIdx.x;
        if (idx < Ssz * 32) {
            const int s = idx >> 5, p = idx & 31;
            const double c = 9.210340371976184257 / 32.0;   // ln(10000)/32
            const double inv = exp(-c * (double)p);
            double sn, cs;
            sincos((double)s * inv, &sn, &cs);
            tc[idx] = (float)cs;
            ts[idx] = (float)sn;
        }
        return;
    }
    const float* s; ushort_t* d;
    switch (blockIdx.z) {
        case 0: s = s0; d = d0; break;
        case 1: s = s1; d = d1; break;
        case 2: s = s2; d = d2; break;
        case 3: s = s3; d = d3; break;
        case 4: s = s4; d = d4; break;
        case 5: s = s5; d = d5; break;
        default: s = s6; d = d6; break;
    }
    const int n = (blockIdx.z < 3) ? n_big : n_small;
    const int i = (blockIdx.x * 256 + threadIdx.x) * 4;
    if (i >= n) return;
    float4 v = *(const float4*)(s + i);
    ushort4 o;
    o.x = bf16_rn(v.x); o.y = bf16_rn(v.y);
    o.z = bf16_rn(v.z); o.w = bf16_rn(v.w);
    *(ushort4*)(d + i) = o;
}

// ---------------------------------------------------------------------------
// Pure-bf16 projection GEMM (tile 128x128, BK=32, 4 waves).  Epilogue tile
// Tb ALIASES sA/sB (safe after the K-loop's closing barrier): LDS 34.8 KB
// -> 4 blocks/CU (was 51 KB / 3).
//   z=0: Q -> RoPE -> *KF -> bf16 [b,h,s,d]
//   z=1: K -> RoPE ->        bf16 [b,h,s,d]
//   z=2: V ->                bf16 [b,h,d,s]
// ---------------------------------------------------------------------------
__global__ __launch_bounds__(256) void proj_gemm_kernel(
    const ushort_t* __restrict__ Aq, const ushort_t* __restrict__ Ak,
    const ushort_t* __restrict__ Av,
    const ushort_t* __restrict__ Wq, const ushort_t* __restrict__ Wk,
    const ushort_t* __restrict__ Wv,
    ushort_t* __restrict__ Yq, ushort_t* __restrict__ Yk,
    ushort_t* __restrict__ Yv,
    const float* __restrict__ tc, const float* __restrict__ ts)
{
    const int z = blockIdx.z;
    const ushort_t* Ag = (z == 0) ? Aq : (z == 1) ? Ak : Av;
    const ushort_t* Wg = (z == 0) ? Wq : (z == 1) ? Wk : Wv;
    ushort_t*       Yg = (z == 0) ? Yq : (z == 1) ? Yk : Yv;

    __shared__ __align__(16) char smem[128 * TP * 2];   // 34816 B
    ushort_t* sA = (ushort_t*)smem;                     // 128*32 shorts
    ushort_t* sB = sA + 128 * 32;                       // 128*32 shorts
    ushort_t* Tb = (ushort_t*)smem;                     // aliases (post-loop)

    const int t    = threadIdx.x;
    const int lane = t & 63;
    const int w    = t >> 6;
    const int wm   = (w & 1) * 64;
    const int wn   = (w >> 1) * 64;
    const int fr   = lane & 15;
    const int g    = lane >> 4;
    const int kq   = g * 8;
    const int n0   = blockIdx.x * 128;
    const int m0   = blockIdx.y * 128;

    const ushort_t* pA = Ag + (size_t)(m0 + (t >> 2)) * 1024 + (t & 3) * 8;
    const ushort_t* pB = Wg + (size_t)(n0 + (t >> 2)) * 1024 + (t & 3) * 8;

    f32x4 acc[4][4];
#pragma unroll
    for (int mi = 0; mi < 4; ++mi)
#pragma unroll
        for (int ni = 0; ni < 4; ++ni) acc[mi][ni] = (f32x4)0.f;

    for (int k0 = 0; k0 < 1024; k0 += 32) {
        GLD16(pA + k0,             &sA[t * 8]);
        GLD16(pA + k0 + 64 * 1024, &sA[2048 + t * 8]);
        GLD16(pB + k0,             &sB[t * 8]);
        GLD16(pB + k0 + 64 * 1024, &sB[2048 + t * 8]);
        __syncthreads();

        bf16x8 a[4], b[4];
#pragma unroll
        for (int mi = 0; mi < 4; ++mi)
            a[mi] = *(const bf16x8*)&sA[(wm + mi * 16 + fr) * 32 + kq];
#pragma unroll
        for (int ni = 0; ni < 4; ++ni)
            b[ni] = *(const bf16x8*)&sB[(wn + ni * 16 + fr) * 32 + kq];
#pragma unroll
        for (int mi = 0; mi < 4; ++mi)
#pragma unroll
            for (int ni = 0; ni < 4; ++ni)
                acc[mi][ni] = MFMA32(a[mi], b[ni], acc[mi][ni]);
        __syncthreads();
    }

    // ---- epilogue: RoPE in-register, stage bf16 tile to LDS (aliased) ----
#pragma unroll
    for (int mi = 0; mi < 4; ++mi)
#pragma unroll
        for (int ni = 0; ni < 4; ++ni) {
            const int col = wn + ni * 16 + fr;          // 0..127
            const int d   = (n0 + col) & 63;
            const int pi  = d >> 1;
#pragma unroll
            for (int rg = 0; rg < 4; ++rg) {
                const int row = wm + mi * 16 + g * 4 + rg;   // 0..127
                const int s   = (m0 + row) & (Ssz - 1);
                float v  = acc[mi][ni][rg];
                float pt = __shfl_xor(v, 1, 64);   // RoPE partner (col^1)
                float o  = v;
                if (z < 2) {
                    const float cs = tc[s * 32 + pi];
                    const float sn = ts[s * 32 + pi];
                    o = (d & 1) ? fmaf(v, cs, pt * sn)
                                : fmaf(v, cs, -pt * sn);
                    if (z == 0) o *= KF;
                }
                Tb[row * TP + col] = bf16_rn(o);
            }
        }
    __syncthreads();

    if (z < 2) {
        // [b,h,s,d]: row -> (b,s); 16 chunks of 8 shorts per row
        const int row = t >> 1;
        const int m   = m0 + row;
        const int b   = m >> 11, s = m & (Ssz - 1);
#pragma unroll
        for (int i = 0; i < 8; ++i) {
            const int ic = (t & 1) * 8 + i;
            uint4 val = *(const uint4*)&Tb[row * TP + ic * 8];
            const int hh = (n0 >> 6) + (ic >> 3);
            const int d  = (ic & 7) * 8;
            *(uint4*)&Yg[(((size_t)(b * Hn + hh)) * Ssz + s) * Dd + d] = val;
        }
    } else {
        // [b,h,d,s]: col -> (h,d); contiguous along s
        const int col = t >> 1;
        const int hh  = (n0 >> 6) + (col >> 6);
        const int d   = col & 63;
        const int b   = m0 >> 11;
        const int sg  = (m0 & (Ssz - 1)) + (t & 1) * 64;
        const size_t base = (((size_t)(b * Hn + hh)) * Dd + d) * Ssz + sg;
#pragma unroll
        for (int jj = 0; jj < 8; ++jj) {
            uint4 val;
            unsigned vv[4];
#pragma unroll
            for (int qd = 0; qd < 4; ++qd) {
                const int r0 = (t & 1) * 64 + jj * 8 + qd * 2;
                const unsigned lo = Tb[(r0 + 0) * TP + col];
                const unsigned hi = Tb[(r0 + 1) * TP + col];
                vv[qd] = lo | (hi << 16);
            }
            val.x = vv[0]; val.y = vv[1]; val.z = vv[2]; val.w = vv[3];
            *(uint4*)&Yg[base + jj * 8] = val;
        }
    }
}

// ---------------------------------------------------------------------------
// Pure-bf16 MFMA flash attention, S^T formulation, DOUBLE-BUFFERED K/V.
// Per KV step: issue next-tile global loads (VGPR), compute QK/exp2/PV on the
// current LDS buffers, ds_write next tile, ONE barrier.  Load latency
// overlaps the whole compute phase (critical at 2 blocks/CU).
// ---------------------------------------------------------------------------
__global__ __launch_bounds__(256) void attn_kernel(
    const ushort_t* __restrict__ Qb, const ushort_t* __restrict__ Kb,
    const ushort_t* __restrict__ Vtb, ushort_t* __restrict__ Ob)
{
    __shared__ __align__(16) ushort_t sKV[4][64 * PADC];  // K0,K1,V0,V1

    const int t    = threadIdx.x;
    const int lane = t & 63;
    const int w    = t >> 6;
    const int fr   = lane & 15;
    const int g    = lane >> 4;
    const int kq   = g * 8;
    const int bh   = blockIdx.y;
    const int q0   = blockIdx.x * 128;

    // Q fragments (B-operand of S^T)
    bf16x8 qa[2][2];
#pragma unroll
    for (int mt = 0; mt < 2; ++mt) {
        const size_t qbase = ((size_t)bh * Ssz + q0 + w * 32 + mt * 16 + fr) * Dd;
        qa[mt][0] = *(const bf16x8*)(Qb + qbase + kq);
        qa[mt][1] = *(const bf16x8*)(Qb + qbase + 32 + kq);
    }

    float lp[2] = {0.f, 0.f};
    f32x4 Oacc[2][4];
#pragma unroll
    for (int mt = 0; mt < 2; ++mt)
#pragma unroll
        for (int dt = 0; dt < 4; ++dt) Oacc[mt][dt] = (f32x4)0.f;

    const int srow = t >> 3;        // 0..31
    const int scol = (t & 7) * 8;
    const size_t kgb = (size_t)bh * Ssz * Dd;
    const size_t vgb = (size_t)bh * Dd * Ssz;

    // prologue: stage tile 0 into buffer 0
#pragma unroll
    for (int rr = 0; rr < 2; ++rr) {
        const int row = srow + rr * 32;
        *(uint4*)&sKV[0][row * PADC + scol] =
            *(const uint4*)(Kb + kgb + (size_t)row * Dd + scol);
        *(uint4*)&sKV[2][row * PADC + scol] =
            *(const uint4*)(Vtb + vgb + (size_t)row * Ssz + scol);
    }
    __syncthreads();

    int cur = 0;
    for (int kv0 = 0; kv0 < Ssz; kv0 += 64) {
        const bool more = (kv0 + 64 < Ssz);
        uint4 nk[2], nv[2];
        if (more) {
#pragma unroll
            for (int rr = 0; rr < 2; ++rr) {
                const int row = srow + rr * 32;
                nk[rr] = *(const uint4*)(Kb + kgb + (size_t)(kv0 + 64 + row) * Dd + scol);
                nv[rr] = *(const uint4*)(Vtb + vgb + (size_t)row * Ssz + kv0 + 64 + scol);
            }
        }
        const ushort_t* sK = sKV[cur];
        const ushort_t* sV = sKV[2 + cur];

        // S^T: A=K (lane fr -> kv), B=Q (lane fr -> q).  16 MFMA32.
        f32x4 St[2][4];
#pragma unroll
        for (int mt = 0; mt < 2; ++mt)
#pragma unroll
            for (int nt = 0; nt < 4; ++nt) St[mt][nt] = (f32x4)0.f;
#pragma unroll
        for (int ks = 0; ks < 2; ++ks)
#pragma unroll
            for (int nt = 0; nt < 4; ++nt) {
                bf16x8 kfrag = *(const bf16x8*)&sK[(nt * 16 + fr) * PADC + ks * 32 + kq];
#pragma unroll
                for (int mt = 0; mt < 2; ++mt)
                    St[mt][nt] = MFMA32(kfrag, qa[mt][ks], St[mt][nt]);
            }

        // exp2 + truncate-pack into 16x16x16 A-fragments (P[q=fr][c=g*4+j])
        bf16x4 pf[2][4];
#pragma unroll
        for (int mt = 0; mt < 2; ++mt)
#pragma unroll
            for (int nt = 0; nt < 4; ++nt) {
                const float p0 = exp2f(St[mt][nt][0]);
                const float p1 = exp2f(St[mt][nt][1]);
                const float p2 = exp2f(St[mt][nt][2]);
                const float p3 = exp2f(St[mt][nt][3]);
                lp[mt] += (p0 + p1) + (p2 + p3);
                union { unsigned u[2]; bf16x4 s; } pk;
                pk.u[0] = (__float_as_uint(p0) >> 16) | (__float_as_uint(p1) & 0xFFFF0000u);
                pk.u[1] = (__float_as_uint(p2) >> 16) | (__float_as_uint(p3) & 0xFFFF0000u);
                pf[mt][nt] = pk.s;
            }

        // PV: B = V^T fragment (b64), 32 MFMA16
#pragma unroll
        for (int nt = 0; nt < 4; ++nt)
#pragma unroll
            for (int dt = 0; dt < 4; ++dt) {
                bf16x4 vfrag = *(const bf16x4*)&sV[(dt * 16 + fr) * PADC + nt * 16 + g * 4];
#pragma unroll
                for (int mt = 0; mt < 2; ++mt)
                    Oacc[mt][dt] = MFMA16(pf[mt][nt], vfrag, Oacc[mt][dt]);
            }

        if (more) {
#pragma unroll
            for (int rr = 0; rr < 2; ++rr) {
                const int row = srow + rr * 32;
                *(uint4*)&sKV[cur ^ 1][row * PADC + scol] = nk[rr];
                *(uint4*)&sKV[2 + (cur ^ 1)][row * PADC + scol] = nv[rr];
            }
            __syncthreads();
            cur ^= 1;
        }
    }

    // reduce row sums across g-groups
#pragma unroll
    for (int mt = 0; mt < 2; ++mt) {
        lp[mt] += __shfl_xor(lp[mt], 16, 64);
        lp[mt] += __shfl_xor(lp[mt], 32, 64);
    }

    // epilogue: O[q = g*4+rg][d = dt*16+fr] -> bf16 [b,s,e]
    const int b = bh >> 4, h = bh & 15;
#pragma unroll
    for (int mt = 0; mt < 2; ++mt)
#pragma unroll
        for (int rg = 0; rg < 4; ++rg) {
            const float lv  = __shfl(lp[mt], (lane & 48) + g * 4 + rg, 64);
            const float inv = 1.f / lv;
            const int s = q0 + w * 32 + mt * 16 + g * 4 + rg;
#pragma unroll
            for (int dt = 0; dt < 4; ++dt) {
                const float o = Oacc[mt][dt][rg] * inv;
                Ob[((size_t)(b * Ssz + s)) * Esz + h * Dd + dt * 16 + fr] = bf16_rn(o);
            }
        }
}

// ---------------------------------------------------------------------------
// Pure-bf16 final GEMM: out = O @ W_o^T, fp32 out.  Tile 128x64 -> 512
// blocks (2/CU resident work, was 1/CU at 128x128).  Epilogue fp32 tile
// ALIASES sA/sB -> LDS 34.8 KB, 4 blocks/CU.
// ---------------------------------------------------------------------------
__global__ __launch_bounds__(256) void final_gemm_kernel(
    const ushort_t* __restrict__ Ag, const ushort_t* __restrict__ Bg,
    float* __restrict__ Yf)
{
    __shared__ __align__(16) char smem[128 * FP * 4];   // 34816 B
    ushort_t* sA = (ushort_t*)smem;                     // 128*32 shorts
    ushort_t* sB = sA + 128 * 32;                       // 64*32 shorts
    float*    Tf = (float*)smem;                        // aliases (post-loop)

    const int t    = threadIdx.x;
    const int lane = t & 63;
    const int w    = t >> 6;
    const int wm   = (w & 1) * 64;
    const int wn   = (w >> 1) * 32;
    const int fr   = lane & 15;
    const int g    = lane >> 4;
    const int kq   = g * 8;
    const int n0   = blockIdx.x * 64;
    const int m0   = blockIdx.y * 128;

    const ushort_t* pA = Ag + (size_t)(m0 + (t >> 2)) * 1024 + (t & 3) * 8;
    const ushort_t* pB = Bg + (size_t)(n0 + (t >> 2)) * 1024 + (t & 3) * 8;

    f32x4 acc[4][2];
#pragma unroll
    for (int mi = 0; mi < 4; ++mi)
#pragma unroll
        for (int ni = 0; ni < 2; ++ni) acc[mi][ni] = (f32x4)0.f;

    for (int k0 = 0; k0 < 1024; k0 += 32) {
        GLD16(pA + k0,             &sA[t * 8]);
        GLD16(pA + k0 + 64 * 1024, &sA[2048 + t * 8]);
        GLD16(pB + k0,             &sB[t * 8]);
        __syncthreads();

        bf16x8 a[4], b[2];
#pragma unroll
        for (int mi = 0; mi < 4; ++mi)
            a[mi] = *(const bf16x8*)&sA[(wm + mi * 16 + fr) * 32 + kq];
#pragma unroll
        for (int ni = 0; ni < 2; ++ni)
            b[ni] = *(const bf16x8*)&sB[(wn + ni * 16 + fr) * 32 + kq];
#pragma unroll
        for (int mi = 0; mi < 4; ++mi)
#pragma unroll
            for (int ni = 0; ni < 2; ++ni)
                acc[mi][ni] = MFMA32(a[mi], b[ni], acc[mi][ni]);
        __syncthreads();
    }

    // epilogue: fp32 tile through aliased LDS -> dense float4 stores
#pragma unroll
    for (int mi = 0; mi < 4; ++mi)
#pragma unroll
        for (int ni = 0; ni < 2; ++ni) {
            const int col = wn + ni * 16 + fr;                // 0..63
#pragma unroll
            for (int rg = 0; rg < 4; ++rg)
                Tf[(wm + mi * 16 + g * 4 + rg) * FP + col] = acc[mi][ni][rg];
        }
    __syncthreads();

    const int row = t >> 1;
    float* dst = Yf + (size_t)(m0 + row) * 1024 + n0 + (t & 1) * 32;
    const float* src = &Tf[row * FP + (t & 1) * 32];
#pragma unroll
    for (int i = 0; i < 8; ++i)
        *(float4*)(dst + i * 4) = *(const float4*)(src + i * 4);
}

// ---------------------------------------------------------------------------
extern "C" void kernel_launch(void* const* d_in, const int* in_sizes, int n_in,
                              void* d_out, int out_size, void* d_ws, size_t ws_size,
                              hipStream_t stream)
{
    (void)in_sizes; (void)n_in; (void)out_size; (void)ws_size;
    const float* q   = (const float*)d_in[0];
    const float* k   = (const float*)d_in[1];
    const float* v   = (const float*)d_in[2];
    const float* W_q = (const float*)d_in[3];
    const float* W_k = (const float*)d_in[4];
    const float* W_v = (const float*)d_in[5];
    const float* W_o = (const float*)d_in[6];
    float* out = (float*)d_out;

    const size_t NQ = (size_t)Bsz * Ssz * Esz;   // 4,194,304
    const size_t NW = (size_t)Esz * Esz;         // 1,048,576

    float* ws = (float*)d_ws;
    float* tc = ws;                  // 65536
    float* ts = ws + 65536;          // 65536

    ushort_t* us  = (ushort_t*)(ws + 131072);
    ushort_t* qb  = us;              // bf16 inputs
    ushort_t* kb  = qb + NQ;
    ushort_t* vb  = kb + NQ;
    ushort_t* wqb = vb + NQ;         // bf16 weights
    ushort_t* wkb = wqb + NW;
    ushort_t* wvb = wkb + NW;
    ushort_t* wob = wvb + NW;
    ushort_t* pq  = wob + NW;        // projected bf16 tensors
    ushort_t* pk  = pq + NQ;
    ushort_t* pv  = pk + NQ;
    ushort_t* ob  = pv + NQ;         // attention output bf16

    dim3 blk(256);

    cvt_kernel<<<dim3(4096, 1, 8), blk, 0, stream>>>(
        q, k, v, W_q, W_k, W_v, W_o,
        qb, kb, vb, wqb, wkb, wvb, wob, tc, ts, (int)NQ, (int)NW);

    proj_gemm_kernel<<<dim3(Esz / 128, (Bsz * Ssz) / 128, 3), blk, 0, stream>>>(
        qb, kb, vb, wqb, wkb, wvb, pq, pk, pv, tc, ts);

    attn_kernel<<<dim3(Ssz / 128, Bsz * Hn), blk, 0, stream>>>(pq, pk, pv, ob);

    final_gemm_kernel<<<dim3(Esz / 64, (Bsz * Ssz) / 128), blk, 0, stream>>>(
        ob, wob, out);
}

// Round 9
// 271.690 us; speedup vs baseline: 1.1115x; 1.1115x over previous
//
#include <hip/hip_runtime.h>
#include <math.h>

#define Bsz 2
#define Ssz 2048
#define Esz 1024
#define Hn  16
#define Dd  64
#define PK   64    // attn LDS pitch in shorts (128 B, XOR-swizzled, GLD16-compatible)
#define TP   136   // proj epilogue LDS tile pitch in shorts (272 B)
#define FP   68    // final epilogue LDS tile pitch in floats (272 B)

typedef unsigned short ushort_t;
typedef short bf16x8 __attribute__((ext_vector_type(8)));
typedef short bf16x4 __attribute__((ext_vector_type(4)));
typedef float f32x4 __attribute__((ext_vector_type(4)));

#define GLD16(g, l) __builtin_amdgcn_global_load_lds(                        \
    (const __attribute__((address_space(1))) unsigned int*)(g),              \
    (__attribute__((address_space(3))) unsigned int*)(l), 16, 0, 0)

#define KF 0.045084220027780106f   // (1/sqrt(E)) * log2(e), folded into Q

#define MFMA32(a, b, c) __builtin_amdgcn_mfma_f32_16x16x32_bf16((a), (b), (c), 0, 0, 0)
#define MFMA16(a, b, c) __builtin_amdgcn_mfma_f32_16x16x16bf16_1k((a), (b), (c), 0, 0, 0)

// ---------------------------------------------------------------------------
__device__ inline ushort_t bf16_rn(float x)
{
    unsigned u = __float_as_uint(x);
    return (ushort_t)((u + 0x7FFFu + ((u >> 16) & 1u)) >> 16);
}

// ---------------------------------------------------------------------------
// fp32 -> bf16 convert (7 tensors) + RoPE table build (z=7).
// ---------------------------------------------------------------------------
__global__ __launch_bounds__(256) void cvt_kernel(
    const float* s0, const float* s1, const float* s2, const float* s3,
    const float* s4, const float* s5, const float* s6,
    ushort_t* d0, ushort_t* d1, ushort_t* d2, ushort_t* d3,
    ushort_t* d4, ushort_t* d5, ushort_t* d6,
    float* tc, float* ts, int n_big, int n_small)
{
    if (blockIdx.z == 7) {
        const int idx = blockIdx.x * 256 + threadIdx.x;
        if (idx < Ssz * 32) {
            const int s = idx >> 5, p = idx & 31;
            const double c = 9.210340371976184257 / 32.0;   // ln(10000)/32
            const double inv = exp(-c * (double)p);
            double sn, cs;
            sincos((double)s * inv, &sn, &cs);
            tc[idx] = (float)cs;
            ts[idx] = (float)sn;
        }
        return;
    }
    const float* s; ushort_t* d;
    switch (blockIdx.z) {
        case 0: s = s0; d = d0; break;
        case 1: s = s1; d = d1; break;
        case 2: s = s2; d = d2; break;
        case 3: s = s3; d = d3; break;
        case 4: s = s4; d = d4; break;
        case 5: s = s5; d = d5; break;
        default: s = s6; d = d6; break;
    }
    const int n = (blockIdx.z < 3) ? n_big : n_small;
    const int i = (blockIdx.x * 256 + threadIdx.x) * 4;
    if (i >= n) return;
    float4 v = *(const float4*)(s + i);
    ushort4 o;
    o.x = bf16_rn(v.x); o.y = bf16_rn(v.y);
    o.z = bf16_rn(v.z); o.w = bf16_rn(v.w);
    *(ushort4*)(d + i) = o;
}

// ---------------------------------------------------------------------------
// Pure-bf16 projection GEMM (tile 128x128, BK=32, 4 waves).  Epilogue tile
// Tb aliases sA/sB: LDS 34.8 KB -> 4 blocks/CU.
//   z=0: Q -> RoPE -> *KF -> bf16 [b,h,s,d]
//   z=1: K -> RoPE ->        bf16 [b,h,s,d]
//   z=2: V ->                bf16 [b,h,d,s]
// ---------------------------------------------------------------------------
__global__ __launch_bounds__(256) void proj_gemm_kernel(
    const ushort_t* __restrict__ Aq, const ushort_t* __restrict__ Ak,
    const ushort_t* __restrict__ Av,
    const ushort_t* __restrict__ Wq, const ushort_t* __restrict__ Wk,
    const ushort_t* __restrict__ Wv,
    ushort_t* __restrict__ Yq, ushort_t* __restrict__ Yk,
    ushort_t* __restrict__ Yv,
    const float* __restrict__ tc, const float* __restrict__ ts)
{
    const int z = blockIdx.z;
    const ushort_t* Ag = (z == 0) ? Aq : (z == 1) ? Ak : Av;
    const ushort_t* Wg = (z == 0) ? Wq : (z == 1) ? Wk : Wv;
    ushort_t*       Yg = (z == 0) ? Yq : (z == 1) ? Yk : Yv;

    __shared__ __align__(16) char smem[128 * TP * 2];   // 34816 B
    ushort_t* sA = (ushort_t*)smem;                     // 128*32 shorts
    ushort_t* sB = sA + 128 * 32;                       // 128*32 shorts
    ushort_t* Tb = (ushort_t*)smem;                     // aliases (post-loop)

    const int t    = threadIdx.x;
    const int lane = t & 63;
    const int w    = t >> 6;
    const int wm   = (w & 1) * 64;
    const int wn   = (w >> 1) * 64;
    const int fr   = lane & 15;
    const int g    = lane >> 4;
    const int kq   = g * 8;
    const int n0   = blockIdx.x * 128;
    const int m0   = blockIdx.y * 128;

    const ushort_t* pA = Ag + (size_t)(m0 + (t >> 2)) * 1024 + (t & 3) * 8;
    const ushort_t* pB = Wg + (size_t)(n0 + (t >> 2)) * 1024 + (t & 3) * 8;

    f32x4 acc[4][4];
#pragma unroll
    for (int mi = 0; mi < 4; ++mi)
#pragma unroll
        for (int ni = 0; ni < 4; ++ni) acc[mi][ni] = (f32x4)0.f;

    for (int k0 = 0; k0 < 1024; k0 += 32) {
        GLD16(pA + k0,             &sA[t * 8]);
        GLD16(pA + k0 + 64 * 1024, &sA[2048 + t * 8]);
        GLD16(pB + k0,             &sB[t * 8]);
        GLD16(pB + k0 + 64 * 1024, &sB[2048 + t * 8]);
        __syncthreads();

        bf16x8 a[4], b[4];
#pragma unroll
        for (int mi = 0; mi < 4; ++mi)
            a[mi] = *(const bf16x8*)&sA[(wm + mi * 16 + fr) * 32 + kq];
#pragma unroll
        for (int ni = 0; ni < 4; ++ni)
            b[ni] = *(const bf16x8*)&sB[(wn + ni * 16 + fr) * 32 + kq];
#pragma unroll
        for (int mi = 0; mi < 4; ++mi)
#pragma unroll
            for (int ni = 0; ni < 4; ++ni)
                acc[mi][ni] = MFMA32(a[mi], b[ni], acc[mi][ni]);
        __syncthreads();
    }

    // ---- epilogue: RoPE in-register, stage bf16 tile to LDS (aliased) ----
#pragma unroll
    for (int mi = 0; mi < 4; ++mi)
#pragma unroll
        for (int ni = 0; ni < 4; ++ni) {
            const int col = wn + ni * 16 + fr;          // 0..127
            const int d   = (n0 + col) & 63;
            const int pi  = d >> 1;
#pragma unroll
            for (int rg = 0; rg < 4; ++rg) {
                const int row = wm + mi * 16 + g * 4 + rg;   // 0..127
                const int s   = (m0 + row) & (Ssz - 1);
                float v  = acc[mi][ni][rg];
                float pt = __shfl_xor(v, 1, 64);   // RoPE partner (col^1)
                float o  = v;
                if (z < 2) {
                    const float cs = tc[s * 32 + pi];
                    const float sn = ts[s * 32 + pi];
                    o = (d & 1) ? fmaf(v, cs, pt * sn)
                                : fmaf(v, cs, -pt * sn);
                    if (z == 0) o *= KF;
                }
                Tb[row * TP + col] = bf16_rn(o);
            }
        }
    __syncthreads();

    if (z < 2) {
        // [b,h,s,d]: row -> (b,s); 16 chunks of 8 shorts per row
        const int row = t >> 1;
        const int m   = m0 + row;
        const int b   = m >> 11, s = m & (Ssz - 1);
#pragma unroll
        for (int i = 0; i < 8; ++i) {
            const int ic = (t & 1) * 8 + i;
            uint4 val = *(const uint4*)&Tb[row * TP + ic * 8];
            const int hh = (n0 >> 6) + (ic >> 3);
            const int d  = (ic & 7) * 8;
            *(uint4*)&Yg[(((size_t)(b * Hn + hh)) * Ssz + s) * Dd + d] = val;
        }
    } else {
        // [b,h,d,s]: col -> (h,d); contiguous along s
        const int col = t >> 1;
        const int hh  = (n0 >> 6) + (col >> 6);
        const int d   = col & 63;
        const int b   = m0 >> 11;
        const int sg  = (m0 & (Ssz - 1)) + (t & 1) * 64;
        const size_t base = (((size_t)(b * Hn + hh)) * Dd + d) * Ssz + sg;
#pragma unroll
        for (int jj = 0; jj < 8; ++jj) {
            uint4 val;
            unsigned vv[4];
#pragma unroll
            for (int qd = 0; qd < 4; ++qd) {
                const int r0 = (t & 1) * 64 + jj * 8 + qd * 2;
                const unsigned lo = Tb[(r0 + 0) * TP + col];
                const unsigned hi = Tb[(r0 + 1) * TP + col];
                vv[qd] = lo | (hi << 16);
            }
            val.x = vv[0]; val.y = vv[1]; val.z = vv[2]; val.w = vv[3];
            *(uint4*)&Yg[base + jj * 8] = val;
        }
    }
}

// ---------------------------------------------------------------------------
// Pure-bf16 MFMA flash attention, S^T formulation, GLD16-double-buffered K/V.
// Per KV step: issue 4 global_load_lds into buffer cur^1 (async DMA, zero
// VGPR cost), compute QK/exp2/PV on buffer cur, ONE barrier (its vmcnt(0)
// drain is the prefetch wait).  LDS layout: pitch 64 shorts, 16-B chunk j of
// row r stored at chunk j^(r&7) — GLD16-compatible (linear lane map) AND
// conflict-free fragment reads (fr sweeps all 8 chunks; 2 lanes/quad).
// ---------------------------------------------------------------------------
__global__ __launch_bounds__(256) void attn_kernel(
    const ushort_t* __restrict__ Qb, const ushort_t* __restrict__ Kb,
    const ushort_t* __restrict__ Vtb, ushort_t* __restrict__ Ob)
{
    __shared__ __align__(16) ushort_t sKV[4][64 * PK];  // K0,K1,V0,V1 (32 KB)

    const int t    = threadIdx.x;
    const int lane = t & 63;
    const int w    = t >> 6;
    const int fr   = lane & 15;
    const int g    = lane >> 4;
    const int kq   = g * 8;
    const int bh   = blockIdx.y;
    const int q0   = blockIdx.x * 128;

    // Q fragments (B-operand of S^T)
    bf16x8 qa[2][2];
#pragma unroll
    for (int mt = 0; mt < 2; ++mt) {
        const size_t qbase = ((size_t)bh * Ssz + q0 + w * 32 + mt * 16 + fr) * Dd;
        qa[mt][0] = *(const bf16x8*)(Qb + qbase + kq);
        qa[mt][1] = *(const bf16x8*)(Qb + qbase + 32 + kq);
    }

    float lp[2] = {0.f, 0.f};
    f32x4 Oacc[2][4];
#pragma unroll
    for (int mt = 0; mt < 2; ++mt)
#pragma unroll
        for (int dt = 0; dt < 4; ++dt) Oacc[mt][dt] = (f32x4)0.f;

    // staging map: thread t covers rows r1 = t>>3 and r1+32, source chunk
    // j1 = (t&7) ^ (r1&7)  (same for both rows since 32&7 == 0)
    const int r1 = t >> 3;
    const int r2 = r1 + 32;
    const int j1 = (t & 7) ^ (r1 & 7);
    const size_t kgb = (size_t)bh * Ssz * Dd;
    const size_t vgb = (size_t)bh * Dd * Ssz;

    // swizzled fragment-read chunk indices (lane constants)
    const int f7 = fr & 7;

    // prologue: DMA tile 0 into buffers 0 (K) and 2 (V)
    GLD16(Kb  + kgb + (size_t)r1 * Dd  + j1 * 8, &sKV[0][t * 8]);
    GLD16(Kb  + kgb + (size_t)r2 * Dd  + j1 * 8, &sKV[0][2048 + t * 8]);
    GLD16(Vtb + vgb + (size_t)r1 * Ssz + j1 * 8, &sKV[2][t * 8]);
    GLD16(Vtb + vgb + (size_t)r2 * Ssz + j1 * 8, &sKV[2][2048 + t * 8]);
    __syncthreads();

    int cur = 0;
    for (int kv0 = 0; kv0 < Ssz; kv0 += 64) {
        const bool more = (kv0 + 64 < Ssz);
        if (more) {
            const int nb = cur ^ 1;
            GLD16(Kb  + kgb + (size_t)(kv0 + 64 + r1) * Dd + j1 * 8,
                  &sKV[nb][t * 8]);
            GLD16(Kb  + kgb + (size_t)(kv0 + 64 + r2) * Dd + j1 * 8,
                  &sKV[nb][2048 + t * 8]);
            GLD16(Vtb + vgb + (size_t)r1 * Ssz + kv0 + 64 + j1 * 8,
                  &sKV[2 + nb][t * 8]);
            GLD16(Vtb + vgb + (size_t)r2 * Ssz + kv0 + 64 + j1 * 8,
                  &sKV[2 + nb][2048 + t * 8]);
        }
        const ushort_t* sK = sKV[cur];
        const ushort_t* sV = sKV[2 + cur];

        // S^T: A=K (lane fr -> kv), B=Q (lane fr -> q).  16 MFMA32.
        f32x4 St[2][4];
#pragma unroll
        for (int mt = 0; mt < 2; ++mt)
#pragma unroll
            for (int nt = 0; nt < 4; ++nt) St[mt][nt] = (f32x4)0.f;
#pragma unroll
        for (int ks = 0; ks < 2; ++ks)
#pragma unroll
            for (int nt = 0; nt < 4; ++nt) {
                const int ch = (ks * 4 + g) ^ f7;       // swizzled 16B chunk
                bf16x8 kfrag = *(const bf16x8*)&sK[(nt * 16 + fr) * PK + ch * 8];
#pragma unroll
                for (int mt = 0; mt < 2; ++mt)
                    St[mt][nt] = MFMA32(kfrag, qa[mt][ks], St[mt][nt]);
            }

        // exp2 + truncate-pack into 16x16x16 A-fragments (P[q=fr][c=g*4+j])
        bf16x4 pf[2][4];
#pragma unroll
        for (int mt = 0; mt < 2; ++mt)
#pragma unroll
            for (int nt = 0; nt < 4; ++nt) {
                const float p0 = exp2f(St[mt][nt][0]);
                const float p1 = exp2f(St[mt][nt][1]);
                const float p2 = exp2f(St[mt][nt][2]);
                const float p3 = exp2f(St[mt][nt][3]);
                lp[mt] += (p0 + p1) + (p2 + p3);
                union { unsigned u[2]; bf16x4 s; } pk;
                pk.u[0] = (__float_as_uint(p0) >> 16) | (__float_as_uint(p1) & 0xFFFF0000u);
                pk.u[1] = (__float_as_uint(p2) >> 16) | (__float_as_uint(p3) & 0xFFFF0000u);
                pf[mt][nt] = pk.s;
            }

        // PV: B = V^T fragment (b64, swizzled), 32 MFMA16
#pragma unroll
        for (int nt = 0; nt < 4; ++nt)
#pragma unroll
            for (int dt = 0; dt < 4; ++dt) {
                const int ch = (2 * nt + (g >> 1)) ^ f7;
                bf16x4 vfrag = *(const bf16x4*)
                    &sV[(dt * 16 + fr) * PK + ch * 8 + (g & 1) * 4];
#pragma unroll
                for (int mt = 0; mt < 2; ++mt)
                    Oacc[mt][dt] = MFMA16(pf[mt][nt], vfrag, Oacc[mt][dt]);
            }

        if (more) {
            __syncthreads();   // drains vmcnt(0): prefetch landed, reads done
            cur ^= 1;
        }
    }

    // reduce row sums across g-groups
#pragma unroll
    for (int mt = 0; mt < 2; ++mt) {
        lp[mt] += __shfl_xor(lp[mt], 16, 64);
        lp[mt] += __shfl_xor(lp[mt], 32, 64);
    }

    // epilogue: O[q = g*4+rg][d = dt*16+fr] -> bf16 [b,s,e]
    const int b = bh >> 4, h = bh & 15;
#pragma unroll
    for (int mt = 0; mt < 2; ++mt)
#pragma unroll
        for (int rg = 0; rg < 4; ++rg) {
            const float lv  = __shfl(lp[mt], (lane & 48) + g * 4 + rg, 64);
            const float inv = 1.f / lv;
            const int s = q0 + w * 32 + mt * 16 + g * 4 + rg;
#pragma unroll
            for (int dt = 0; dt < 4; ++dt) {
                const float o = Oacc[mt][dt][rg] * inv;
                Ob[((size_t)(b * Ssz + s)) * Esz + h * Dd + dt * 16 + fr] = bf16_rn(o);
            }
        }
}

// ---------------------------------------------------------------------------
// Pure-bf16 final GEMM: out = O @ W_o^T, fp32 out.  Tile 128x64, epilogue
// fp32 tile aliases sA/sB -> LDS 34.8 KB, 512 blocks.
// ---------------------------------------------------------------------------
__global__ __launch_bounds__(256) void final_gemm_kernel(
    const ushort_t* __restrict__ Ag, const ushort_t* __restrict__ Bg,
    float* __restrict__ Yf)
{
    __shared__ __align__(16) char smem[128 * FP * 4];   // 34816 B
    ushort_t* sA = (ushort_t*)smem;                     // 128*32 shorts
    ushort_t* sB = sA + 128 * 32;                       // 64*32 shorts
    float*    Tf = (float*)smem;                        // aliases (post-loop)

    const int t    = threadIdx.x;
    const int lane = t & 63;
    const int w    = t >> 6;
    const int wm   = (w & 1) * 64;
    const int wn   = (w >> 1) * 32;
    const int fr   = lane & 15;
    const int g    = lane >> 4;
    const int kq   = g * 8;
    const int n0   = blockIdx.x * 64;
    const int m0   = blockIdx.y * 128;

    const ushort_t* pA = Ag + (size_t)(m0 + (t >> 2)) * 1024 + (t & 3) * 8;
    const ushort_t* pB = Bg + (size_t)(n0 + (t >> 2)) * 1024 + (t & 3) * 8;

    f32x4 acc[4][2];
#pragma unroll
    for (int mi = 0; mi < 4; ++mi)
#pragma unroll
        for (int ni = 0; ni < 2; ++ni) acc[mi][ni] = (f32x4)0.f;

    for (int k0 = 0; k0 < 1024; k0 += 32) {
        GLD16(pA + k0,             &sA[t * 8]);
        GLD16(pA + k0 + 64 * 1024, &sA[2048 + t * 8]);
        GLD16(pB + k0,             &sB[t * 8]);
        __syncthreads();

        bf16x8 a[4], b[2];
#pragma unroll
        for (int mi = 0; mi < 4; ++mi)
            a[mi] = *(const bf16x8*)&sA[(wm + mi * 16 + fr) * 32 + kq];
#pragma unroll
        for (int ni = 0; ni < 2; ++ni)
            b[ni] = *(const bf16x8*)&sB[(wn + ni * 16 + fr) * 32 + kq];
#pragma unroll
        for (int mi = 0; mi < 4; ++mi)
#pragma unroll
            for (int ni = 0; ni < 2; ++ni)
                acc[mi][ni] = MFMA32(a[mi], b[ni], acc[mi][ni]);
        __syncthreads();
    }

    // epilogue: fp32 tile through aliased LDS -> dense float4 stores
#pragma unroll
    for (int mi = 0; mi < 4; ++mi)
#pragma unroll
        for (int ni = 0; ni < 2; ++ni) {
            const int col = wn + ni * 16 + fr;                // 0..63
#pragma unroll
            for (int rg = 0; rg < 4; ++rg)
                Tf[(wm + mi * 16 + g * 4 + rg) * FP + col] = acc[mi][ni][rg];
        }
    __syncthreads();

    const int row = t >> 1;
    float* dst = Yf + (size_t)(m0 + row) * 1024 + n0 + (t & 1) * 32;
    const float* src = &Tf[row * FP + (t & 1) * 32];
#pragma unroll
    for (int i = 0; i < 8; ++i)
        *(float4*)(dst + i * 4) = *(const float4*)(src + i * 4);
}

// ---------------------------------------------------------------------------
extern "C" void kernel_launch(void* const* d_in, const int* in_sizes, int n_in,
                              void* d_out, int out_size, void* d_ws, size_t ws_size,
                              hipStream_t stream)
{
    (void)in_sizes; (void)n_in; (void)out_size; (void)ws_size;
    const float* q   = (const float*)d_in[0];
    const float* k   = (const float*)d_in[1];
    const float* v   = (const float*)d_in[2];
    const float* W_q = (const float*)d_in[3];
    const float* W_k = (const float*)d_in[4];
    const float* W_v = (const float*)d_in[5];
    const float* W_o = (const float*)d_in[6];
    float* out = (float*)d_out;

    const size_t NQ = (size_t)Bsz * Ssz * Esz;   // 4,194,304
    const size_t NW = (size_t)Esz * Esz;         // 1,048,576

    float* ws = (float*)d_ws;
    float* tc = ws;                  // 65536
    float* ts = ws + 65536;          // 65536

    ushort_t* us  = (ushort_t*)(ws + 131072);
    ushort_t* qb  = us;              // bf16 inputs
    ushort_t* kb  = qb + NQ;
    ushort_t* vb  = kb + NQ;
    ushort_t* wqb = vb + NQ;         // bf16 weights
    ushort_t* wkb = wqb + NW;
    ushort_t* wvb = wkb + NW;
    ushort_t* wob = wvb + NW;
    ushort_t* pq  = wob + NW;        // projected bf16 tensors
    ushort_t* pk  = pq + NQ;
    ushort_t* pv  = pk + NQ;
    ushort_t* ob  = pv + NQ;         // attention output bf16

    dim3 blk(256);

    cvt_kernel<<<dim3(4096, 1, 8), blk, 0, stream>>>(
        q, k, v, W_q, W_k, W_v, W_o,
        qb, kb, vb, wqb, wkb, wvb, wob, tc, ts, (int)NQ, (int)NW);

    proj_gemm_kernel<<<dim3(Esz / 128, (Bsz * Ssz) / 128, 3), blk, 0, stream>>>(
        qb, kb, vb, wqb, wkb, wvb, pq, pk, pv, tc, ts);

    attn_kernel<<<dim3(Ssz / 128, Bsz * Hn), blk, 0, stream>>>(pq, pk, pv, ob);

    final_gemm_kernel<<<dim3(Esz / 64, (Bsz * Ssz) / 128), blk, 0, stream>>>(
        ob, wob, out);
}